// Round 15
// baseline (300.261 us; speedup 1.0000x reference)
//
#include <hip/hip_runtime.h>
#include <cstdint>
#include <cstddef>

#define HH 768
#define SS 512
#define NBATCH 8
#define NLH 12
#define HDIM 64
#define BSROWS 4096
static constexpr float NEGV = -1000000000000.0f;

typedef unsigned short ushort_t;
typedef __attribute__((ext_vector_type(4))) float fx4;
typedef __attribute__((ext_vector_type(8))) short sx8;

__device__ __forceinline__ ushort_t f2bf(float f) {
  uint32_t u = __float_as_uint(f);
  uint32_t r = (u + 0x7FFFu + ((u >> 16) & 1u)) >> 16;
  return (ushort_t)r;
}
__device__ __forceinline__ float bf2f(ushort_t h) {
  return __uint_as_float(((uint32_t)h) << 16);
}
__device__ __forceinline__ float2 ldbf2(const ushort_t* p) {
  uint32_t u = *(const uint32_t*)p;
  return make_float2(__uint_as_float(u << 16), __uint_as_float(u & 0xffff0000u));
}

__device__ __forceinline__ void async_copy16(void* lds, const void* g) {
  __builtin_amdgcn_global_load_lds(
      (const __attribute__((address_space(1))) void*)g,
      (__attribute__((address_space(3))) void*)lds, 16, 0, 0);
}

// ============ GEMM core: 128x128 tile, BK=64, 4 waves, XCD swizzle over nwg
__device__ __forceinline__ void gemm_core(
    char* arena, int bid, int nwg, int nx,
    const ushort_t* __restrict__ A, int lda,
    const ushort_t* __restrict__ B, int ldb,
    const float* __restrict__ bias,
    const ushort_t* __restrict__ resb,
    ushort_t* __restrict__ Cb, int ldo,
    ushort_t* __restrict__ Cb2, int ldo2, int nsplit, int K,
    float* __restrict__ colmean)
{
  ushort_t* As = (ushort_t*)arena;
  ushort_t* Bs = (ushort_t*)(arena + 16384);
  const int tid = threadIdx.x;
  const int q = nwg >> 3;
  const int xcd = bid & 7, sidx = bid >> 3;
  const int swz = xcd * q + sidx;
  const int bm = (swz / nx) * 128;
  const int bn = (swz % nx) * 128;
  const int l = tid & 63;
  const int w = tid >> 6;
  const int wr = w >> 1, wc = w & 1;
  const int r8 = tid >> 3;
  const int sl = tid & 7;

  fx4 acc[4][4];
#pragma unroll
  for (int m = 0; m < 4; ++m)
#pragma unroll
    for (int n = 0; n < 4; ++n) acc[m][n] = (fx4)0.f;

  for (int k0 = 0; k0 < K; k0 += 64) {
#pragma unroll
    for (int i = 0; i < 4; ++i) {
      int row = i * 32 + r8;
      int srcs = sl ^ (row & 7);
      async_copy16((char*)As + i * 4096 + tid * 16,
                   A + (size_t)(bm + row) * lda + k0 + srcs * 8);
    }
#pragma unroll
    for (int i = 0; i < 4; ++i) {
      int row = i * 32 + r8;
      int srcs = sl ^ (row & 7);
      async_copy16((char*)Bs + i * 4096 + tid * 16,
                   B + (size_t)(bn + row) * ldb + k0 + srcs * 8);
    }
    __syncthreads();
#pragma unroll
    for (int kk = 0; kk < 2; ++kk) {
      sx8 av[4], bv[4];
      const int so = (l >> 4) + kk * 4;
#pragma unroll
      for (int m = 0; m < 4; ++m) {
        int r = wr * 64 + m * 16 + (l & 15);
        av[m] = *(const sx8*)((const char*)As + r * 128 + ((so ^ (r & 7)) * 16));
      }
#pragma unroll
      for (int n = 0; n < 4; ++n) {
        int r = wc * 64 + n * 16 + (l & 15);
        bv[n] = *(const sx8*)((const char*)Bs + r * 128 + ((so ^ (r & 7)) * 16));
      }
#pragma unroll
      for (int m = 0; m < 4; ++m)
#pragma unroll
        for (int n = 0; n < 4; ++n)
          acc[m][n] = __builtin_amdgcn_mfma_f32_16x16x32_bf16(av[m], bv[n], acc[m][n], 0, 0, 0);
    }
    __syncthreads();
  }

  const bool second = (bn >= nsplit);
  ushort_t* dst = second ? Cb2 : Cb;
  const int ld = second ? ldo2 : ldo;
  const int csub = second ? nsplit : 0;
  const int cr0 = bm + wr * 64 + (l >> 4) * 4;
  const int cc0 = bn + wc * 64 + (l & 15);
#pragma unroll
  for (int m = 0; m < 4; ++m) {
#pragma unroll
    for (int n = 0; n < 4; ++n) {
      int col = cc0 + n * 16;
      float bcol = bias[col];
#pragma unroll
      for (int j = 0; j < 4; ++j) {
        int row = cr0 + m * 16 + j;
        size_t off = (size_t)row * ld + (col - csub);
        float v = acc[m][n][j] + bcol;
        if (resb) v += bf2f(resb[off]);
        dst[off] = f2bf(v);
      }
    }
  }

  if (colmean) {
    float* scr = (float*)arena;   // 8 x 128 floats
    const int cid = wr * 4 + (l >> 4);
#pragma unroll
    for (int n = 0; n < 4; ++n) {
      int colL = wc * 64 + n * 16 + (l & 15);
      float t = 16.0f * bias[bn + colL];
#pragma unroll
      for (int m = 0; m < 4; ++m)
#pragma unroll
        for (int j = 0; j < 4; ++j) t += acc[m][n][j];
      scr[cid * 128 + colL] = t;
    }
    __syncthreads();
    if (tid < 128) {
      float scol = 0.f;
#pragma unroll
      for (int c = 0; c < 8; ++c) scol += scr[c * 128 + tid];
      atomicAdd(&colmean[(bm >> 9) * HH + bn + tid], scol * (1.0f / 512.0f));
    }
  }
}

// ============ weight transpose tile core (uses arena)
struct TJob { const float* src; ushort_t* dst; int K, N, Kpad, rowOff; };
__device__ __forceinline__ void transpose_core(char* arena, TJob jb, int k0, int n0)
{
  typedef float TArr[33];
  TArr* t = (TArr*)arena;
  int tx = threadIdx.x & 31, ty = threadIdx.x >> 5;
#pragma unroll
  for (int i = 0; i < 4; ++i) {
    int k = k0 + ty + i * 8;
    float v = 0.f;
    if (k < jb.K && n0 + tx < jb.N) v = jb.src[(size_t)k * jb.N + n0 + tx];
    t[ty + i * 8][tx] = v;
  }
  __syncthreads();
#pragma unroll
  for (int i = 0; i < 4; ++i) {
    int n = n0 + ty + i * 8;
    int k = k0 + tx;
    if (n < jb.N && k < jb.Kpad)
      jb.dst[(size_t)(jb.rowOff + n) * jb.Kpad + k] = f2bf(t[tx][ty + i * 8]);
  }
}

// ============ skinny core: M=8, K=768, 32 cols per block (f32 weights)
struct SmallJob { const float* W; const float* bias; const float* res; float* C; };
struct SmallJobs { SmallJob j[5]; };

__device__ __forceinline__ void skinny_core(
    char* arena, int colblk,
    const float* __restrict__ A, const float* __restrict__ W,
    const float* __restrict__ bias, const float* __restrict__ res, float* __restrict__ C)
{
  float* As = (float*)arena;              // 8*768 = 24KB
  float* part = (float*)(arena + 24576);  // 8KB
  const int tid = threadIdx.x;
#pragma unroll
  for (int i = 0; i < 6; ++i) {
    int idx = tid * 4 + i * 1024;
    *(float4*)&As[idx] = *(const float4*)(A + idx);
  }
  __syncthreads();
  const int c = tid & 31;
  const int col = (colblk << 5) + c;
  const int ks = tid >> 5;
  const float* Wp = W + (size_t)(ks * 96) * HH + col;
  float acc[8] = {};
#pragma unroll 8
  for (int k = 0; k < 96; ++k) {
    float wv = Wp[(size_t)k * HH];
    const float* ap = &As[ks * 96 + k];
#pragma unroll
    for (int m = 0; m < 8; ++m)
      acc[m] = fmaf(ap[m * HH], wv, acc[m]);
  }
#pragma unroll
  for (int m = 0; m < 8; ++m)
    part[ks * 256 + m * 32 + c] = acc[m];
  __syncthreads();
  const int m = tid >> 5;
  const int c2 = tid & 31;
  float s = 0.f;
#pragma unroll
  for (int k = 0; k < 8; ++k) s += part[k * 256 + m * 32 + c2];
  const int outcol = (colblk << 5) + c2;
  float v = s + bias[outcol];
  if (res) v += res[(size_t)m * HH + outcol];
  C[(size_t)m * HH + outcol] = v;
}

// ============ rel attention core: per (b,h), scores->softmax->PV->project(atomicAdd relo)
__device__ __forceinline__ void rel_core(
    char* arena, int b, int h,
    const float* __restrict__ Qr, const float* __restrict__ Krc, const ushort_t* __restrict__ Kr,
    const float* __restrict__ Vrc, const ushort_t* __restrict__ Vr,
    const float* __restrict__ rel_ow, float* __restrict__ relo)
{
  float* qs = (float*)arena;               // 64
  float* sc = (float*)(arena + 256);       // 513
  float* part = (float*)(arena + 2560);    // 4*64
  float* redm = (float*)(arena + 3584);    // 4
  float* redsum = (float*)(arena + 3600);  // 4
  float* ctxs = (float*)(arena + 3616);    // 64
  int t = threadIdx.x, lane = t & 63, wave = t >> 6;
  if (t < 64) qs[t] = Qr[b * HH + h * HDIM + t];
  __syncthreads();
  for (int j = t; j < 513; j += 256) {
    float acc = 0.f;
    if (j == 0) {
      const float* kp = Krc + b * HH + h * HDIM;
#pragma unroll
      for (int d = 0; d < HDIM; ++d) acc = fmaf(qs[d], kp[d], acc);
    } else {
      const sx8* kv = (const sx8*)(Kr + (size_t)(b * SS + j - 1) * 1536 + h * HDIM);
#pragma unroll
      for (int dq = 0; dq < 8; ++dq) {
        sx8 v = kv[dq];
#pragma unroll
        for (int e = 0; e < 8; ++e)
          acc = fmaf(qs[dq * 8 + e], bf2f((ushort_t)v[e]), acc);
      }
    }
    sc[j] = acc * 0.125f;
  }
  __syncthreads();
  float m = -1e30f;
  for (int j = t; j < 513; j += 256) m = fmaxf(m, sc[j]);
#pragma unroll
  for (int d = 1; d < 64; d <<= 1) m = fmaxf(m, __shfl_xor(m, d));
  if (lane == 0) redm[wave] = m;
  __syncthreads();
  m = fmaxf(fmaxf(redm[0], redm[1]), fmaxf(redm[2], redm[3]));
  float lsum = 0.f;
  for (int j = t; j < 513; j += 256) { float e = __expf(sc[j] - m); sc[j] = e; lsum += e; }
#pragma unroll
  for (int d = 1; d < 64; d <<= 1) lsum += __shfl_xor(lsum, d);
  if (lane == 0) redsum[wave] = lsum;
  __syncthreads();
  float total = redsum[0] + redsum[1] + redsum[2] + redsum[3];
  float accv = 0.f;
#pragma unroll 8
  for (int j = wave; j < 513; j += 4) {
    float vv = (j == 0) ? Vrc[b * HH + h * HDIM + lane]
                        : bf2f(Vr[(size_t)(b * SS + j - 1) * 1536 + h * HDIM + lane]);
    accv = fmaf(sc[j], vv, accv);
  }
  part[wave * 64 + lane] = accv;
  __syncthreads();
  if (wave == 0)
    ctxs[lane] = (part[0 * 64 + lane] + part[1 * 64 + lane] +
                  part[2 * 64 + lane] + part[3 * 64 + lane]) / total;
  __syncthreads();
  for (int c = t; c < HH; c += 256) {
    const float* Wp = rel_ow + (size_t)(h * 64) * HH + c;
    float a0 = 0.f, a1 = 0.f, a2 = 0.f, a3 = 0.f;
#pragma unroll
    for (int d = 0; d < 64; d += 4) {
      a0 = fmaf(ctxs[d + 0], Wp[(size_t)(d + 0) * HH], a0);
      a1 = fmaf(ctxs[d + 1], Wp[(size_t)(d + 1) * HH], a1);
      a2 = fmaf(ctxs[d + 2], Wp[(size_t)(d + 2) * HH], a2);
      a3 = fmaf(ctxs[d + 3], Wp[(size_t)(d + 3) * HH], a3);
    }
    atomicAdd(&relo[b * HH + c], (a0 + a1) + (a2 + a3));
  }
}

// ============ standalone GEMM wrapper
__global__ __launch_bounds__(256) void gemm_bf16(
    const ushort_t* __restrict__ A, int lda,
    const ushort_t* __restrict__ B, int ldb,
    const float* __restrict__ bias,
    const ushort_t* __restrict__ resb,
    ushort_t* __restrict__ Cb, int ldo,
    ushort_t* __restrict__ Cb2, int ldo2, int nsplit, int K, int nx,
    float* __restrict__ colmean)
{
  __shared__ char arena[32768];
  gemm_core(arena, blockIdx.x, gridDim.x, nx, A, lda, B, ldb, bias, resb,
            Cb, ldo, Cb2, ldo2, nsplit, K, colmean);
}

// ============ standalone rel attention (96 blocks)
__global__ __launch_bounds__(256) void rel_standalone(
    const float* __restrict__ Qr, const float* __restrict__ Krc,
    const ushort_t* __restrict__ Kr,
    const float* __restrict__ Vrc, const ushort_t* __restrict__ Vr,
    const float* __restrict__ rel_ow, float* __restrict__ relo)
{
  __shared__ char arena[4096];
  rel_core(arena, blockIdx.x / 12, blockIdx.x % 12, Qr, Krc, Kr, Vrc, Vr, rel_ow, relo);
}

// ============ mega: dense GEMM (blocks 0..191) + 7 weight transposes (192..3743)
struct TJobs7 { TJob j[7]; };
__global__ __launch_bounds__(256) void dense_mega(
    const ushort_t* __restrict__ A, const ushort_t* __restrict__ B,
    const float* __restrict__ bias, ushort_t* __restrict__ Cb,
    float* __restrict__ colmean, TJobs7 tj)
{
  __shared__ char arena[32768];
  if (blockIdx.x < 192) {
    gemm_core(arena, blockIdx.x, 192, 6, A, 448, B, 448, bias, nullptr,
              Cb, HH, nullptr, 0, 1 << 30, 448, colmean);
  } else {
    int vb = blockIdx.x - 192;
    if (vb < 3456) {
      TJob jb = tj.j[vb / 576];
      int r = vb % 576;
      transpose_core(arena, jb, (r / 24) * 32, (r % 24) * 32);
    } else {
      int r = vb - 3456;
      transpose_core(arena, tj.j[6], (r / 4) * 32, (r % 4) * 32);
    }
  }
}

// ============ mega: QKV1 GEMM (blocks 0..575) + 5 center skinny jobs (576..695)
__global__ __launch_bounds__(256) void qkv_center(
    const ushort_t* __restrict__ A, const ushort_t* __restrict__ B,
    const float* __restrict__ bias, ushort_t* __restrict__ Cb,
    SmallJobs jobs, const float* __restrict__ center)
{
  __shared__ char arena[32768];
  if (blockIdx.x < 576) {
    gemm_core(arena, blockIdx.x, 576, 18, A, HH, B, HH, bias, nullptr,
              Cb, 2304, nullptr, 0, 1 << 30, HH, nullptr);
  } else {
    int vb = blockIdx.x - 576;
    SmallJob jb = jobs.j[vb / 24];
    skinny_core(arena, vb % 24, center, jb.W, jb.bias, jb.res, jb.C);
  }
}

// ============ skinny with in-block relu+LN of (relo + rel_ob + center)
struct SmallJobs2 { SmallJob j[2]; };
__global__ __launch_bounds__(256) void skinny_ln(
    const float* __restrict__ relo, const float* __restrict__ rel_ob,
    const float* __restrict__ center,
    const float* __restrict__ lw, const float* __restrict__ lb,
    SmallJobs2 jobs)
{
  __shared__ float As[8 * HH];
  __shared__ float part[8 * 8 * 32];
  const int tid = threadIdx.x;
  const SmallJob job = jobs.j[blockIdx.y];
#pragma unroll
  for (int i = 0; i < 6; ++i) {
    int idx = tid * 4 + i * 1024;
    int row = idx / HH;
    int col = idx - row * HH;
    float4 r4 = *(const float4*)(relo + idx);
    float4 o4 = *(const float4*)(rel_ob + col);
    float4 c4 = *(const float4*)(center + idx);
    As[idx + 0] = r4.x + o4.x + c4.x;
    As[idx + 1] = r4.y + o4.y + c4.y;
    As[idx + 2] = r4.z + o4.z + c4.z;
    As[idx + 3] = r4.w + o4.w + c4.w;
  }
  __syncthreads();
  {
    const int row = tid >> 5, lc = tid & 31;
    float s = 0.f, sq = 0.f;
#pragma unroll
    for (int e = 0; e < 24; ++e) {
      float x = fmaxf(As[row * HH + lc * 24 + e], 0.f);
      s += x; sq += x * x;
    }
#pragma unroll
    for (int d = 1; d < 32; d <<= 1) { s += __shfl_xor(s, d); sq += __shfl_xor(sq, d); }
    float mean = s * (1.0f / HH);
    float var = sq * (1.0f / HH) - mean * mean;
    float rstd = rsqrtf(var + 1e-12f);
#pragma unroll
    for (int e = 0; e < 24; ++e) {
      int cc = lc * 24 + e;
      float x = fmaxf(As[row * HH + cc], 0.f);
      As[row * HH + cc] = lw[cc] * (x - mean) * rstd + lb[cc];
    }
  }
  __syncthreads();
  const int c = tid & 31;
  const int col = (blockIdx.x << 5) + c;
  const int ks = tid >> 5;
  const float* Wp = job.W + (size_t)(ks * 96) * HH + col;
  float acc[8] = {};
#pragma unroll 8
  for (int k = 0; k < 96; ++k) {
    float wv = Wp[(size_t)k * HH];
    const float* ap = &As[ks * 96 + k];
#pragma unroll
    for (int m = 0; m < 8; ++m)
      acc[m] = fmaf(ap[m * HH], wv, acc[m]);
  }
#pragma unroll
  for (int m = 0; m < 8; ++m)
    part[ks * 256 + m * 32 + c] = acc[m];
  __syncthreads();
  const int m = tid >> 5;
  const int c2 = tid & 31;
  float s2 = 0.f;
#pragma unroll
  for (int k = 0; k < 8; ++k) s2 += part[k * 256 + m * 32 + c2];
  const int outcol = (blockIdx.x << 5) + c2;
  job.C[(size_t)m * HH + outcol] = s2 + job.bias[outcol];
}

// ============ fused head: relu+LN -> GEMM -> RoPE + tail, 16 rows/block x 256 blocks
__global__ __launch_bounds__(256) void head_fused(
    const ushort_t* __restrict__ Araw,
    const float* __restrict__ lnw, const float* __restrict__ lnb,
    const ushort_t* __restrict__ B,
    const float* __restrict__ head_b,
    const float* __restrict__ tail_w,
    const float* __restrict__ tail_b,
    float* __restrict__ qw, float* __restrict__ kw,
    float* __restrict__ bias2)
{
  __shared__ ushort_t As[16 * 64];
  __shared__ ushort_t Bs[128 * 64];
  __shared__ float tile[16][130];
  __shared__ float invt[32];
  __shared__ float2 rst[16];
  const int tid = threadIdx.x;
  const int bm = blockIdx.x * 16;
  const int l = tid & 63;
  const int w = tid >> 6;
  const int r8 = tid >> 3;
  const int sl = tid & 7;

  if (tid < 32) invt[tid] = powf(10000.0f, -(float)tid / 32.0f);

  {
    int row = tid >> 4, part = tid & 15;
    const ushort_t* rp = Araw + (size_t)(bm + row) * HH + part * 48;
    float s = 0.f, sq = 0.f;
#pragma unroll
    for (int c = 0; c < 6; ++c) {
      sx8 v = *(const sx8*)(rp + c * 8);
#pragma unroll
      for (int e = 0; e < 8; ++e) {
        float x = fmaxf(bf2f((ushort_t)v[e]), 0.f);
        s += x; sq += x * x;
      }
    }
#pragma unroll
    for (int d = 1; d < 16; d <<= 1) { s += __shfl_xor(s, d); sq += __shfl_xor(sq, d); }
    if (part == 0) {
      float mean = s * (1.0f / HH);
      float var = sq * (1.0f / HH) - mean * mean;
      rst[row] = make_float2(mean, rsqrtf(var + 1e-12f));
    }
  }
  __syncthreads();

  fx4 acc[2];
  acc[0] = (fx4)0.f; acc[1] = (fx4)0.f;

  for (int k0 = 0; k0 < HH; k0 += 64) {
#pragma unroll
    for (int i = 0; i < 4; ++i) {
      int row = i * 32 + r8;
      int srcs = sl ^ (row & 7);
      async_copy16((char*)Bs + i * 4096 + tid * 16,
                   B + (size_t)row * HH + k0 + srcs * 8);
    }
    if (tid < 128) {
      int row = tid >> 3;
      int slot = sl ^ (row & 7);
      int gk = k0 + slot * 8;
      sx8 v = *(const sx8*)(Araw + (size_t)(bm + row) * HH + gk);
      float4 w0 = *(const float4*)(lnw + gk);
      float4 w1 = *(const float4*)(lnw + gk + 4);
      float4 b0 = *(const float4*)(lnb + gk);
      float4 b1 = *(const float4*)(lnb + gk + 4);
      float wv[8] = {w0.x, w0.y, w0.z, w0.w, w1.x, w1.y, w1.z, w1.w};
      float bv[8] = {b0.x, b0.y, b0.z, b0.w, b1.x, b1.y, b1.z, b1.w};
      float2 mr = rst[row];
      sx8 ov;
#pragma unroll
      for (int e = 0; e < 8; ++e) {
        float x = fmaxf(bf2f((ushort_t)v[e]), 0.f);
        ov[e] = (short)f2bf(fmaf((x - mr.x) * mr.y, wv[e], bv[e]));
      }
      *(sx8*)((char*)As + row * 128 + sl * 16) = ov;
    }
    __syncthreads();
#pragma unroll
    for (int kk = 0; kk < 2; ++kk) {
      const int so = (l >> 4) + kk * 4;
      int ra = l & 15;
      sx8 av = *(const sx8*)((const char*)As + ra * 128 + ((so ^ (ra & 7)) * 16));
#pragma unroll
      for (int n = 0; n < 2; ++n) {
        int r = w * 32 + n * 16 + (l & 15);
        sx8 bv = *(const sx8*)((const char*)Bs + r * 128 + ((so ^ (r & 7)) * 16));
        acc[n] = __builtin_amdgcn_mfma_f32_16x16x32_bf16(av, bv, acc[n], 0, 0, 0);
      }
    }
    __syncthreads();
  }

  {
    const int rr0 = (l >> 4) * 4;
#pragma unroll
    for (int n = 0; n < 2; ++n) {
      int col = w * 32 + n * 16 + (l & 15);
      float bcol = head_b[col];
#pragma unroll
      for (int j = 0; j < 4; ++j)
        tile[rr0 + j][col] = acc[n][j] + bcol;
    }
  }
  __syncthreads();

#pragma unroll
  for (int it = 0; it < 2; ++it) {
    int t = tid + it * 256;
    int r = t >> 5, i = t & 31;
    int s = (bm + r) & 511;
    float ang = (float)s * invt[i];
    float sn = sinf(ang), cn = cosf(ang);
    float q0 = tile[r][4 * i + 0], k0 = tile[r][4 * i + 1];
    float q1 = tile[r][4 * i + 2], k1 = tile[r][4 * i + 3];
    float* qp = qw + (size_t)(bm + r) * 64 + i * 2;
    float* kp = kw + (size_t)(bm + r) * 64 + i * 2;
    qp[0] = q0 * cn - q1 * sn; qp[1] = q1 * cn + q0 * sn;
    kp[0] = k0 * cn - k1 * sn; kp[1] = k1 * cn + k0 * sn;
  }
  for (int t = tid; t < 16 * 24; t += 256) {
    int r = t / 24, c = t % 24;
    float acc2 = tail_b[c];
#pragma unroll 16
    for (int k = 0; k < 128; ++k) acc2 = fmaf(tile[r][k], tail_w[k * 24 + c], acc2);
    bias2[(size_t)(bm + r) * 24 + c] = acc2 * 0.5f;
  }
}

// ============ prep: z==0 dense_w transpose, z==1 misc (bert->bf16, biases, zeros)
struct PrepArgs {
  TJob j0;
  const float* bert; ushort_t* bert_bf;
  const float* rkb; const float* rvb; const float* sqb; const float* skb; const float* svb;
  float* b_merged;
  float* center;
  float* relo;
};
__global__ __launch_bounds__(256) void prep_all(PrepArgs pa)
{
  if (blockIdx.z == 0) {
    __shared__ char arena[4356];
    transpose_core(arena, pa.j0, blockIdx.x * 32, blockIdx.y * 32);
  } else {
    const int NB = BSROWS * 448;
    const int total = NB + 3840 + 2 * NBATCH * HH;
    int start = (blockIdx.y * 24 + blockIdx.x) * 256 + threadIdx.x;
    for (int i = start; i < total; i += 24 * 24 * 256) {
      if (i < NB) {
        int r = i / 448, c = i % 448;
        pa.bert_bf[i] = (c < 432) ? f2bf(pa.bert[(size_t)r * 432 + c]) : (ushort_t)0;
      } else if (i < NB + 3840) {
        int c = i - NB;
        float v;
        if (c < 768) v = pa.rkb[c];
        else if (c < 1536) v = pa.rvb[c - 768];
        else if (c < 2304) v = pa.sqb[c - 1536];
        else if (c < 3072) v = pa.skb[c - 2304];
        else v = pa.svb[c - 3072];
        pa.b_merged[c] = v;
      } else if (i < NB + 3840 + NBATCH * HH) {
        pa.center[i - NB - 3840] = 0.f;
      } else {
        pa.relo[i - NB - 3840 - NBATCH * HH] = 0.f;
      }
    }
  }
}

// ============ star attention, ushort2-vectorized, XCD-chunked blockIdx swizzle
__global__ __launch_bounds__(256) void sat_attn(
    const ushort_t* __restrict__ Qc, const ushort_t* __restrict__ Kc,
    const ushort_t* __restrict__ Vc, int ldq,
    const ushort_t* __restrict__ Kh0, const ushort_t* __restrict__ Vh0, int ldh,
    const float* __restrict__ Kcen, const float* __restrict__ Vcen,
    ushort_t* __restrict__ ctxb)
{
  int i = ((blockIdx.x & 7) << 9) | (blockIdx.x >> 3);
  int b = i >> 9, s = i & 511;
  int lane = threadIdx.x & 63;
  int wave = threadIdx.x >> 6;
  size_t rb = (size_t)(b * SS + ((s + 1) & 511));
  size_t rs = (size_t)i;
  size_t ra = (size_t)(b * SS + (s == 0 ? (SS - 1) : 0));
  size_t rc = (size_t)b * HH;
  const int half = lane >> 5;
  const int d0 = (lane & 31) * 2;
#pragma unroll
  for (int it = 0; it < 2; ++it) {
    int p = wave + 4 * it;
    if (p >= 6) break;
    int off = (2 * p + half) * HDIM + d0;
    float2 q  = ldbf2(Qc + rs * ldq + off);
    float2 kb = ldbf2(Kc + rb * ldq + off);
    float2 ks = ldbf2(Kc + rs * ldq + off);
    float2 ka = ldbf2(Kc + ra * ldq + off);
    float2 kh = ldbf2(Kh0 + rs * ldh + off);
    float2 kc = *(const float2*)(Kcen + rc + off);
    float s0 = q.x * kb.x + q.y * kb.y;
    float s1 = q.x * ks.x + q.y * ks.y;
    float s2 = q.x * ka.x + q.y * ka.y;
    float s3 = q.x * kh.x + q.y * kh.y;
    float s4 = q.x * kc.x + q.y * kc.y;
#pragma unroll
    for (int d = 1; d < 32; d <<= 1) {
      s0 += __shfl_xor(s0, d); s1 += __shfl_xor(s1, d); s2 += __shfl_xor(s2, d);
      s3 += __shfl_xor(s3, d); s4 += __shfl_xor(s4, d);
    }
    const float sc = 0.125f;
    s0 *= sc; s1 *= sc; s2 *= sc; s3 *= sc; s4 *= sc;
    float mx = fmaxf(fmaxf(fmaxf(s0, s1), fmaxf(s2, s3)), s4);
    float e0 = __expf(s0 - mx), e1 = __expf(s1 - mx), e2 = __expf(s2 - mx);
    float e3 = __expf(s3 - mx), e4 = __expf(s4 - mx);
    float inv = 1.f / (e0 + e1 + e2 + e3 + e4);
    float2 vb = ldbf2(Vc + rb * ldq + off);
    float2 vs = ldbf2(Vc + rs * ldq + off);
    float2 va = ldbf2(Vc + ra * ldq + off);
    float2 vh = ldbf2(Vh0 + rs * ldh + off);
    float2 vc = *(const float2*)(Vcen + rc + off);
    float vx = e0 * vb.x + e1 * vs.x + e2 * va.x + e3 * vh.x + e4 * vc.x;
    float vy = e0 * vb.y + e1 * vs.y + e2 * va.y + e3 * vh.y + e4 * vc.y;
    uint32_t o = (uint32_t)f2bf(vx * inv) | ((uint32_t)f2bf(vy * inv) << 16);
    *(uint32_t*)(ctxb + rs * HH + off) = o;
  }
}

// ============ relu + layernorm over bf16 rows -> bf16 (iter-1 only)
__global__ __launch_bounds__(256) void relu_ln_bf(
    const ushort_t* __restrict__ x, const float* __restrict__ w, const float* __restrict__ b,
    ushort_t* __restrict__ ybf)
{
  int row = blockIdx.x;
  const ushort_t* xr = x + (size_t)row * HH;
  float v[3];
  float sum = 0.f, sumsq = 0.f;
#pragma unroll
  for (int j = 0; j < 3; ++j) {
    float t = bf2f(xr[threadIdx.x + j * 256]);
    t = fmaxf(t, 0.f);
    v[j] = t;
    sum += t; sumsq += t * t;
  }
#pragma unroll
  for (int d = 1; d < 64; d <<= 1) { sum += __shfl_xor(sum, d); sumsq += __shfl_xor(sumsq, d); }
  __shared__ float ws_[4], wsq_[4];
  int wave = threadIdx.x >> 6, lane = threadIdx.x & 63;
  if (lane == 0) { ws_[wave] = sum; wsq_[wave] = sumsq; }
  __syncthreads();
  sum = ws_[0] + ws_[1] + ws_[2] + ws_[3];
  sumsq = wsq_[0] + wsq_[1] + wsq_[2] + wsq_[3];
  float mean = sum * (1.0f / HH);
  float var = sumsq * (1.0f / HH) - mean * mean;
  float rstd = rsqrtf(var + 1e-12f);
#pragma unroll
  for (int j = 0; j < 3; ++j) {
    int cidx = threadIdx.x + j * 256;
    float o = w[cidx] * (v[j] - mean) * rstd + b[cidx];
    ybf[(size_t)row * HH + cidx] = f2bf(o);
  }
}

// ============ final logits
__global__ __launch_bounds__(256) void final_kernel(
    const float* __restrict__ qw, const float* __restrict__ kw,
    const float* __restrict__ bias2, const float* __restrict__ mask,
    float* __restrict__ out)
{
  int b = blockIdx.z;
  int mt = blockIdx.y * 32;
  int nt = blockIdx.x * 32;
  __shared__ float qs[32][68];
  __shared__ float ks[32][68];
  int t = threadIdx.x;
  {
    int idx = t * 8;
    int r = idx >> 6, c = idx & 63;
    const float* sq = qw + (size_t)(b * SS + mt + r) * 64 + c;
    const float* sk = kw + (size_t)(b * SS + nt + r) * 64 + c;
    *(float4*)&qs[r][c]     = *(const float4*)(sq);
    *(float4*)&qs[r][c + 4] = *(const float4*)(sq + 4);
    *(float4*)&ks[r][c]     = *(const float4*)(sk);
    *(float4*)&ks[r][c + 4] = *(const float4*)(sk + 4);
  }
  __syncthreads();
  int m = t >> 3;
  int n0 = (t & 7) * 4;
  float d0 = 0.f, d1 = 0.f, d2 = 0.f, d3 = 0.f;
#pragma unroll
  for (int d = 0; d < 64; d += 4) {
    float4 qv = *(const float4*)&qs[m][d];
    float4 k0 = *(const float4*)&ks[n0 + 0][d];
    float4 k1 = *(const float4*)&ks[n0 + 1][d];
    float4 k2 = *(const float4*)&ks[n0 + 2][d];
    float4 k3 = *(const float4*)&ks[n0 + 3][d];
    d0 += qv.x * k0.x + qv.y * k0.y + qv.z * k0.z + qv.w * k0.w;
    d1 += qv.x * k1.x + qv.y * k1.y + qv.z * k1.z + qv.w * k1.w;
    d2 += qv.x * k2.x + qv.y * k2.y + qv.z * k2.z + qv.w * k2.w;
    d3 += qv.x * k3.x + qv.y * k3.y + qv.z * k3.z + qv.w * k3.w;
  }
  int gm = mt + m;
  int gn = nt + n0;
  d0 *= 0.125f; d1 *= 0.125f; d2 *= 0.125f; d3 *= 0.125f;
  float mm = mask[b * SS + gm];
  float mn0 = mask[b * SS + gn + 0];
  float mn1 = mask[b * SS + gn + 1];
  float mn2 = mask[b * SS + gn + 2];
  float mn3 = mask[b * SS + gn + 3];
  const float* bmp  = bias2 + (size_t)(b * SS + gm) * 24;
  const float* bnp0 = bias2 + (size_t)(b * SS + gn + 0) * 24;
  const float* bnp1 = bias2 + (size_t)(b * SS + gn + 1) * 24;
  const float* bnp2 = bias2 + (size_t)(b * SS + gn + 2) * 24;
  const float* bnp3 = bias2 + (size_t)(b * SS + gn + 3) * 24;
#pragma unroll
  for (int h = 0; h < NLH; ++h) {
    float tb = bmp[2 * h + 1];
    float v0 = d0 + bnp0[2 * h] + tb;
    float v1 = d1 + bnp1[2 * h] + tb;
    float v2 = d2 + bnp2[2 * h] + tb;
    float v3 = d3 + bnp3[2 * h] + tb;
    v0 = v0 * mm + NEGV * (1.f - mm); v1 = v1 * mm + NEGV * (1.f - mm);
    v2 = v2 * mm + NEGV * (1.f - mm); v3 = v3 * mm + NEGV * (1.f - mm);
    v0 = v0 * mn0 + NEGV * (1.f - mn0); v1 = v1 * mn1 + NEGV * (1.f - mn1);
    v2 = v2 * mn2 + NEGV * (1.f - mn2); v3 = v3 * mn3 + NEGV * (1.f - mn3);
    if (gm > gn + 0) v0 -= 1000000000000.0f;
    if (gm > gn + 1) v1 -= 1000000000000.0f;
    if (gm > gn + 2) v2 -= 1000000000000.0f;
    if (gm > gn + 3) v3 -= 1000000000000.0f;
    float4 o = make_float4(v0, v1, v2, v3);
    *(float4*)(out + ((((size_t)(b * NLH + h)) * SS + gm) * SS + gn)) = o;
  }
}

extern "C" void kernel_launch(void* const* d_in, const int* in_sizes, int n_in,
                              void* d_out, int out_size, void* d_ws, size_t ws_size,
                              hipStream_t stream)
{
  const float* bert    = (const float*)d_in[0];
  const float* amask   = (const float*)d_in[1];
  const float* dense_w = (const float*)d_in[2];
  const float* dense_b = (const float*)d_in[3];
  const float* sat_qw  = (const float*)d_in[4];
  const float* sat_qb  = (const float*)d_in[5];
  const float* sat_kw  = (const float*)d_in[6];
  const float* sat_kb  = (const float*)d_in[7];
  const float* sat_vw  = (const float*)d_in[8];
  const float* sat_vb  = (const float*)d_in[9];
  const float* sat_ow  = (const float*)d_in[10];
  const float* sat_ob  = (const float*)d_in[11];
  const float* rel_qw  = (const float*)d_in[12];
  const float* rel_qb  = (const float*)d_in[13];
  const float* rel_kw  = (const float*)d_in[14];
  const float* rel_kb  = (const float*)d_in[15];
  const float* rel_vw  = (const float*)d_in[16];
  const float* rel_vb  = (const float*)d_in[17];
  const float* rel_ow  = (const float*)d_in[18];
  const float* rel_ob  = (const float*)d_in[19];
  const float* lns_w   = (const float*)d_in[20];
  const float* lns_b   = (const float*)d_in[21];
  const float* lnr_w   = (const float*)d_in[22];
  const float* lnr_b   = (const float*)d_in[23];
  const float* head_w  = (const float*)d_in[24];
  const float* head_b  = (const float*)d_in[25];
  const float* tail_w  = (const float*)d_in[26];
  const float* tail_b  = (const float*)d_in[27];

  float* out = (float*)d_out;
  char*  ws  = (char*)d_ws;

  size_t off = 0;
  auto alloc = [&](size_t bytes) { char* p = ws + off; off += (bytes + 255) & ~(size_t)255; return p; };
  ushort_t* bert_bf   = (ushort_t*)alloc((size_t)BSROWS * 448 * 2);
  ushort_t* Wt_dense  = (ushort_t*)alloc((size_t)768 * 448 * 2);
  ushort_t* Wt_big    = (ushort_t*)alloc((size_t)3840 * 768 * 2);
  ushort_t* Wt_satow  = (ushort_t*)alloc((size_t)768 * 768 * 2);
  ushort_t* Wt_head   = (ushort_t*)alloc((size_t)128 * 768 * 2);
  ushort_t* hidden0_bf= (ushort_t*)alloc((size_t)BSROWS * HH * 2);
  ushort_t* ctx_bf    = (ushort_t*)alloc((size_t)BSROWS * HH * 2);
  ushort_t* csA_bf    = (ushort_t*)alloc((size_t)BSROWS * HH * 2);
  float* b_merged = (float*)alloc(3840 * 4);
  float* center   = (float*)alloc(6144 * 4);
  float* Kcen     = (float*)alloc(6144 * 4);
  float* Vcen     = (float*)alloc(6144 * 4);
  float* Qr       = (float*)alloc(6144 * 4);
  float* Krc      = (float*)alloc(6144 * 4);
  float* Vrc      = (float*)alloc(6144 * 4);
  float* relo     = (float*)alloc(6144 * 4);
  float* bias2    = (float*)alloc((size_t)BSROWS * 24 * 4);
  float* qwbuf    = (float*)alloc((size_t)BSROWS * 64 * 4);
  float* kwbuf    = (float*)alloc((size_t)BSROWS * 64 * 4);

  ushort_t* QKV1_bf = (ushort_t*)out;
  ushort_t* tmp1_bf = QKV1_bf + (size_t)BSROWS * 2304;
  ushort_t* KrVr_bf = tmp1_bf + (size_t)BSROWS * 768;
  ushort_t* QKV2_bf = KrVr_bf + (size_t)BSROWS * 1536;
  ushort_t* tmp2_bf = tmp1_bf;

  dim3 blk(256);

  // 1. prep: dense_w transpose + misc (+ zero center, relo)
  {
    PrepArgs pa;
    pa.j0 = { dense_w, Wt_dense, 432, 768, 448, 0 };
    pa.bert = bert; pa.bert_bf = bert_bf;
    pa.rkb = rel_kb; pa.rvb = rel_vb; pa.sqb = sat_qb; pa.skb = sat_kb; pa.svb = sat_vb;
    pa.b_merged = b_merged; pa.center = center; pa.relo = relo;
    prep_all<<<dim3(24, 24, 2), blk, 0, stream>>>(pa);
  }

  // 2. dense GEMM (192, 128^2 tile) + column-mean + 7 weight transposes hidden
  {
    TJobs7 tj;
    tj.j[0] = { rel_kw,  Wt_big,   768, 768, 768, 0 };
    tj.j[1] = { rel_vw,  Wt_big,   768, 768, 768, 768 };
    tj.j[2] = { sat_qw,  Wt_big,   768, 768, 768, 1536 };
    tj.j[3] = { sat_kw,  Wt_big,   768, 768, 768, 2304 };
    tj.j[4] = { sat_vw,  Wt_big,   768, 768, 768, 3072 };
    tj.j[5] = { sat_ow,  Wt_satow, 768, 768, 768, 0 };
    tj.j[6] = { head_w,  Wt_head,  768, 128, 768, 0 };
    dense_mega<<<dim3(3744), blk, 0, stream>>>(bert_bf, Wt_dense, dense_b,
                                               hidden0_bf, center, tj);
  }

  // 3. mega: iter-1 QKV GEMM (576) + 5 center skinny projections (120)
  {
    SmallJobs jobs;
    jobs.j[0] = { sat_kw, sat_kb, nullptr, Kcen };
    jobs.j[1] = { sat_vw, sat_vb, nullptr, Vcen };
    jobs.j[2] = { rel_qw, rel_qb, nullptr, Qr };
    jobs.j[3] = { rel_kw, rel_kb, nullptr, Krc };
    jobs.j[4] = { rel_vw, rel_vb, nullptr, Vrc };
    qkv_center<<<dim3(696), blk, 0, stream>>>(hidden0_bf, Wt_big + (size_t)1536 * 768,
                                              b_merged + 1536, QKV1_bf, jobs, center);
  }
  // 4. star attention 1
  sat_attn<<<BSROWS, 256, 0, stream>>>(QKV1_bf, QKV1_bf + 768, QKV1_bf + 1536, 2304,
                                       QKV1_bf + 768, QKV1_bf + 1536, 2304,
                                       Kcen, Vcen, ctx_bf);
  // 5. sat output proj + residual (192 blocks)
  gemm_bf16<<<dim3(192), blk, 0, stream>>>(ctx_bf, HH, Wt_satow, HH, sat_ob,
                                           hidden0_bf, tmp1_bf, HH,
                                           nullptr, 0, 1 << 30, HH, 6, nullptr);
  // 6. relu+LN -> csA
  relu_ln_bf<<<BSROWS, 256, 0, stream>>>(tmp1_bf, lns_w, lns_b, csA_bf);

  // 7. merged relKV + iter-2 QKV GEMM (960 blocks, N=3840 split at 1536)
  gemm_bf16<<<dim3(960), blk, 0, stream>>>(csA_bf, HH, Wt_big, HH, b_merged,
                                           nullptr, KrVr_bf, 1536,
                                           QKV2_bf, 2304, 1536, HH, 30, nullptr);
  // 8. rel attention (96 blocks, ~6 us)
  rel_standalone<<<dim3(96), blk, 0, stream>>>(Qr, Krc, KrVr_bf, Vrc, KrVr_bf + 768,
                                               rel_ow, relo);
  // 9. fused relu+LN(relo+ob+center) + iter-2 center projections
  {
    SmallJobs2 jobs;
    jobs.j[0] = { sat_kw, sat_kb, nullptr, Kcen };
    jobs.j[1] = { sat_vw, sat_vb, nullptr, Vcen };
    skinny_ln<<<dim3(24, 2), blk, 0, stream>>>(relo, rel_ob, center, lnr_w, lnr_b, jobs);
  }
  // 10. star attention 2
  sat_attn<<<BSROWS, 256, 0, stream>>>(QKV2_bf, QKV2_bf + 768, QKV2_bf + 1536, 2304,
                                       QKV1_bf + 768, QKV1_bf + 1536, 2304,
                                       Kcen, Vcen, ctx_bf);
  // 11. sat output proj 2 + residual (raw pre-LN out to tmp2)
  gemm_bf16<<<dim3(192), blk, 0, stream>>>(ctx_bf, HH, Wt_satow, HH, sat_ob,
                                           csA_bf, tmp2_bf, HH,
                                           nullptr, 0, 1 << 30, HH, 6, nullptr);
  // 12. fused relu+LN + head GEMM + rope + tail
  head_fused<<<256, blk, 0, stream>>>(tmp2_bf, lns_w, lns_b, Wt_head, head_b,
                                      tail_w, tail_b, qwbuf, kwbuf, bias2);
  // 13. final logits
  final_kernel<<<dim3(16, 16, 8), 256, 0, stream>>>(qwbuf, kwbuf, bias2, amask, out);
}

// Round 16
// 256.458 us; speedup vs baseline: 1.1708x; 1.1708x over previous
//
#include <hip/hip_runtime.h>
#include <cstdint>
#include <cstddef>

#define HH 768
#define SS 512
#define NBATCH 8
#define NLH 12
#define HDIM 64
#define BSROWS 4096
static constexpr float NEGV = -1000000000000.0f;

typedef unsigned short ushort_t;
typedef __attribute__((ext_vector_type(4))) float fx4;
typedef __attribute__((ext_vector_type(8))) short sx8;

__device__ __forceinline__ ushort_t f2bf(float f) {
  uint32_t u = __float_as_uint(f);
  uint32_t r = (u + 0x7FFFu + ((u >> 16) & 1u)) >> 16;
  return (ushort_t)r;
}
__device__ __forceinline__ float bf2f(ushort_t h) {
  return __uint_as_float(((uint32_t)h) << 16);
}
__device__ __forceinline__ float2 ldbf2(const ushort_t* p) {
  uint32_t u = *(const uint32_t*)p;
  return make_float2(__uint_as_float(u << 16), __uint_as_float(u & 0xffff0000u));
}

__device__ __forceinline__ void async_copy16(void* lds, const void* g) {
  __builtin_amdgcn_global_load_lds(
      (const __attribute__((address_space(1))) void*)g,
      (__attribute__((address_space(3))) void*)lds, 16, 0, 0);
}

// ============ shared GEMM core: 128x128 tile, BK=64, 4 waves, XCD swizzle over nwg
__device__ __forceinline__ void gemm_core(
    char* arena, int bid, int nwg, int nx,
    const ushort_t* __restrict__ A, int lda,
    const ushort_t* __restrict__ B, int ldb,
    const float* __restrict__ bias,
    const ushort_t* __restrict__ resb,
    ushort_t* __restrict__ Cb, int ldo,
    ushort_t* __restrict__ Cb2, int ldo2, int nsplit, int K,
    float* __restrict__ colmean)
{
  ushort_t* As = (ushort_t*)arena;
  ushort_t* Bs = (ushort_t*)(arena + 16384);
  const int tid = threadIdx.x;
  const int q = nwg >> 3;
  const int xcd = bid & 7, sidx = bid >> 3;
  const int swz = xcd * q + sidx;
  const int bm = (swz / nx) * 128;
  const int bn = (swz % nx) * 128;
  const int l = tid & 63;
  const int w = tid >> 6;
  const int wr = w >> 1, wc = w & 1;
  const int r8 = tid >> 3;
  const int sl = tid & 7;

  fx4 acc[4][4];
#pragma unroll
  for (int m = 0; m < 4; ++m)
#pragma unroll
    for (int n = 0; n < 4; ++n) acc[m][n] = (fx4)0.f;

  for (int k0 = 0; k0 < K; k0 += 64) {
#pragma unroll
    for (int i = 0; i < 4; ++i) {
      int row = i * 32 + r8;
      int srcs = sl ^ (row & 7);
      async_copy16((char*)As + i * 4096 + tid * 16,
                   A + (size_t)(bm + row) * lda + k0 + srcs * 8);
    }
#pragma unroll
    for (int i = 0; i < 4; ++i) {
      int row = i * 32 + r8;
      int srcs = sl ^ (row & 7);
      async_copy16((char*)Bs + i * 4096 + tid * 16,
                   B + (size_t)(bn + row) * ldb + k0 + srcs * 8);
    }
    __syncthreads();
#pragma unroll
    for (int kk = 0; kk < 2; ++kk) {
      sx8 av[4], bv[4];
      const int so = (l >> 4) + kk * 4;
#pragma unroll
      for (int m = 0; m < 4; ++m) {
        int r = wr * 64 + m * 16 + (l & 15);
        av[m] = *(const sx8*)((const char*)As + r * 128 + ((so ^ (r & 7)) * 16));
      }
#pragma unroll
      for (int n = 0; n < 4; ++n) {
        int r = wc * 64 + n * 16 + (l & 15);
        bv[n] = *(const sx8*)((const char*)Bs + r * 128 + ((so ^ (r & 7)) * 16));
      }
#pragma unroll
      for (int m = 0; m < 4; ++m)
#pragma unroll
        for (int n = 0; n < 4; ++n)
          acc[m][n] = __builtin_amdgcn_mfma_f32_16x16x32_bf16(av[m], bv[n], acc[m][n], 0, 0, 0);
    }
    __syncthreads();
  }

  const bool second = (bn >= nsplit);
  ushort_t* dst = second ? Cb2 : Cb;
  const int ld = second ? ldo2 : ldo;
  const int csub = second ? nsplit : 0;
  const int cr0 = bm + wr * 64 + (l >> 4) * 4;
  const int cc0 = bn + wc * 64 + (l & 15);
#pragma unroll
  for (int m = 0; m < 4; ++m) {
#pragma unroll
    for (int n = 0; n < 4; ++n) {
      int col = cc0 + n * 16;
      float bcol = bias[col];
#pragma unroll
      for (int j = 0; j < 4; ++j) {
        int row = cr0 + m * 16 + j;
        size_t off = (size_t)row * ld + (col - csub);
        float v = acc[m][n][j] + bcol;
        if (resb) v += bf2f(resb[off]);
        dst[off] = f2bf(v);
      }
    }
  }

  if (colmean) {
    float* scr = (float*)arena;   // 8 x 128 floats
    const int cid = wr * 4 + (l >> 4);
#pragma unroll
    for (int n = 0; n < 4; ++n) {
      int colL = wc * 64 + n * 16 + (l & 15);
      float t = 16.0f * bias[bn + colL];
#pragma unroll
      for (int m = 0; m < 4; ++m)
#pragma unroll
        for (int j = 0; j < 4; ++j) t += acc[m][n][j];
      scr[cid * 128 + colL] = t;
    }
    __syncthreads();
    if (tid < 128) {
      float scol = 0.f;
#pragma unroll
      for (int c = 0; c < 8; ++c) scol += scr[c * 128 + tid];
      atomicAdd(&colmean[(bm >> 9) * HH + bn + tid], scol * (1.0f / 512.0f));
    }
  }
}

// ============ skinny core: M=8, K=768, 32 cols per block (f32 weights)
struct SmallJob { const float* W; const float* bias; const float* res; float* C; };
struct SmallJobs { SmallJob j[5]; };

__device__ __forceinline__ void skinny_core(
    char* arena, int colblk,
    const float* __restrict__ A, const float* __restrict__ W,
    const float* __restrict__ bias, const float* __restrict__ res, float* __restrict__ C)
{
  float* As = (float*)arena;              // 8*768 = 24KB
  float* part = (float*)(arena + 24576);  // 8KB
  const int tid = threadIdx.x;
#pragma unroll
  for (int i = 0; i < 6; ++i) {
    int idx = tid * 4 + i * 1024;
    *(float4*)&As[idx] = *(const float4*)(A + idx);
  }
  __syncthreads();
  const int c = tid & 31;
  const int col = (colblk << 5) + c;
  const int ks = tid >> 5;
  const float* Wp = W + (size_t)(ks * 96) * HH + col;
  float acc[8] = {};
#pragma unroll 8
  for (int k = 0; k < 96; ++k) {
    float wv = Wp[(size_t)k * HH];
    const float* ap = &As[ks * 96 + k];
#pragma unroll
    for (int m = 0; m < 8; ++m)
      acc[m] = fmaf(ap[m * HH], wv, acc[m]);
  }
#pragma unroll
  for (int m = 0; m < 8; ++m)
    part[ks * 256 + m * 32 + c] = acc[m];
  __syncthreads();
  const int m = tid >> 5;
  const int c2 = tid & 31;
  float s = 0.f;
#pragma unroll
  for (int k = 0; k < 8; ++k) s += part[k * 256 + m * 32 + c2];
  const int outcol = (colblk << 5) + c2;
  float v = s + bias[outcol];
  if (res) v += res[(size_t)m * HH + outcol];
  C[(size_t)m * HH + outcol] = v;
}

// ============ rel attention core: per (b,h), scores->softmax->PV->project(atomicAdd relo)
__device__ __forceinline__ void rel_core(
    char* arena, int b, int h,
    const float* __restrict__ Qr, const float* __restrict__ Krc, const ushort_t* __restrict__ Kr,
    const float* __restrict__ Vrc, const ushort_t* __restrict__ Vr,
    const float* __restrict__ rel_ow, float* __restrict__ relo)
{
  float* qs = (float*)arena;               // 64
  float* sc = (float*)(arena + 256);       // 513
  float* part = (float*)(arena + 2560);    // 4*64
  float* redm = (float*)(arena + 3584);    // 4
  float* redsum = (float*)(arena + 3600);  // 4
  float* ctxs = (float*)(arena + 3616);    // 64
  int t = threadIdx.x, lane = t & 63, wave = t >> 6;
  if (t < 64) qs[t] = Qr[b * HH + h * HDIM + t];
  __syncthreads();
  for (int j = t; j < 513; j += 256) {
    float acc = 0.f;
    if (j == 0) {
      const float* kp = Krc + b * HH + h * HDIM;
#pragma unroll
      for (int d = 0; d < HDIM; ++d) acc = fmaf(qs[d], kp[d], acc);
    } else {
      const sx8* kv = (const sx8*)(Kr + (size_t)(b * SS + j - 1) * 1536 + h * HDIM);
#pragma unroll
      for (int dq = 0; dq < 8; ++dq) {
        sx8 v = kv[dq];
#pragma unroll
        for (int e = 0; e < 8; ++e)
          acc = fmaf(qs[dq * 8 + e], bf2f((ushort_t)v[e]), acc);
      }
    }
    sc[j] = acc * 0.125f;
  }
  __syncthreads();
  float m = -1e30f;
  for (int j = t; j < 513; j += 256) m = fmaxf(m, sc[j]);
#pragma unroll
  for (int d = 1; d < 64; d <<= 1) m = fmaxf(m, __shfl_xor(m, d));
  if (lane == 0) redm[wave] = m;
  __syncthreads();
  m = fmaxf(fmaxf(redm[0], redm[1]), fmaxf(redm[2], redm[3]));
  float lsum = 0.f;
  for (int j = t; j < 513; j += 256) { float e = __expf(sc[j] - m); sc[j] = e; lsum += e; }
#pragma unroll
  for (int d = 1; d < 64; d <<= 1) lsum += __shfl_xor(lsum, d);
  if (lane == 0) redsum[wave] = lsum;
  __syncthreads();
  float total = redsum[0] + redsum[1] + redsum[2] + redsum[3];
  float accv = 0.f;
#pragma unroll 8
  for (int j = wave; j < 513; j += 4) {
    float vv = (j == 0) ? Vrc[b * HH + h * HDIM + lane]
                        : bf2f(Vr[(size_t)(b * SS + j - 1) * 1536 + h * HDIM + lane]);
    accv = fmaf(sc[j], vv, accv);
  }
  part[wave * 64 + lane] = accv;
  __syncthreads();
  if (wave == 0)
    ctxs[lane] = (part[0 * 64 + lane] + part[1 * 64 + lane] +
                  part[2 * 64 + lane] + part[3 * 64 + lane]) / total;
  __syncthreads();
  // projection: relo[b][c] += sum_d ctxs[d] * rel_ow[h*64+d][c]
  for (int c = t; c < HH; c += 256) {
    const float* Wp = rel_ow + (size_t)(h * 64) * HH + c;
    float a0 = 0.f, a1 = 0.f, a2 = 0.f, a3 = 0.f;
#pragma unroll
    for (int d = 0; d < 64; d += 4) {
      a0 = fmaf(ctxs[d + 0], Wp[(size_t)(d + 0) * HH], a0);
      a1 = fmaf(ctxs[d + 1], Wp[(size_t)(d + 1) * HH], a1);
      a2 = fmaf(ctxs[d + 2], Wp[(size_t)(d + 2) * HH], a2);
      a3 = fmaf(ctxs[d + 3], Wp[(size_t)(d + 3) * HH], a3);
    }
    atomicAdd(&relo[b * HH + c], (a0 + a1) + (a2 + a3));
  }
}

// ============ standalone GEMM wrapper
__global__ __launch_bounds__(256) void gemm_bf16(
    const ushort_t* __restrict__ A, int lda,
    const ushort_t* __restrict__ B, int ldb,
    const float* __restrict__ bias,
    const ushort_t* __restrict__ resb,
    ushort_t* __restrict__ Cb, int ldo,
    ushort_t* __restrict__ Cb2, int ldo2, int nsplit, int K, int nx,
    float* __restrict__ colmean)
{
  __shared__ char arena[32768];
  gemm_core(arena, blockIdx.x, gridDim.x, nx, A, lda, B, ldb, bias, resb,
            Cb, ldo, Cb2, ldo2, nsplit, K, colmean);
}

// ============ mega: QKV1 GEMM (blocks 0..575) + 5 center skinny jobs (576..695)
__global__ __launch_bounds__(256) void qkv_center(
    const ushort_t* __restrict__ A, const ushort_t* __restrict__ B,
    const float* __restrict__ bias, ushort_t* __restrict__ Cb,
    SmallJobs jobs, const float* __restrict__ center)
{
  __shared__ char arena[32768];
  if (blockIdx.x < 576) {
    gemm_core(arena, blockIdx.x, 576, 18, A, HH, B, HH, bias, nullptr,
              Cb, 2304, nullptr, 0, 1 << 30, HH, nullptr);
  } else {
    int vb = blockIdx.x - 576;
    SmallJob jb = jobs.j[vb / 24];
    skinny_core(arena, vb % 24, center, jb.W, jb.bias, jb.res, jb.C);
  }
}

// ============ mega: QKV2 GEMM (blocks 0..575) + rel attention (576..671)
__global__ __launch_bounds__(256) void qkv2_rel(
    const ushort_t* __restrict__ A, const ushort_t* __restrict__ B,
    const float* __restrict__ bias, ushort_t* __restrict__ Cb,
    const float* __restrict__ Qr, const float* __restrict__ Krc,
    const ushort_t* __restrict__ Kr,
    const float* __restrict__ Vrc, const ushort_t* __restrict__ Vr,
    const float* __restrict__ rel_ow, float* __restrict__ relo)
{
  __shared__ char arena[32768];
  if (blockIdx.x < 576) {
    gemm_core(arena, blockIdx.x, 576, 18, A, HH, B, HH, bias, nullptr,
              Cb, 2304, nullptr, 0, 1 << 30, HH, nullptr);
  } else {
    int v = blockIdx.x - 576;           // 0..95
    rel_core(arena, v / 12, v % 12, Qr, Krc, Kr, Vrc, Vr, rel_ow, relo);
  }
}

// ============ skinny with in-block relu+LN of (relo + rel_ob + center)
struct SmallJobs2 { SmallJob j[2]; };
__global__ __launch_bounds__(256) void skinny_ln(
    const float* __restrict__ relo, const float* __restrict__ rel_ob,
    const float* __restrict__ center,
    const float* __restrict__ lw, const float* __restrict__ lb,
    SmallJobs2 jobs)
{
  __shared__ float As[8 * HH];
  __shared__ float part[8 * 8 * 32];
  const int tid = threadIdx.x;
  const SmallJob job = jobs.j[blockIdx.y];
#pragma unroll
  for (int i = 0; i < 6; ++i) {
    int idx = tid * 4 + i * 1024;
    int row = idx / HH;
    int col = idx - row * HH;
    float4 r4 = *(const float4*)(relo + idx);
    float4 o4 = *(const float4*)(rel_ob + col);
    float4 c4 = *(const float4*)(center + idx);
    As[idx + 0] = r4.x + o4.x + c4.x;
    As[idx + 1] = r4.y + o4.y + c4.y;
    As[idx + 2] = r4.z + o4.z + c4.z;
    As[idx + 3] = r4.w + o4.w + c4.w;
  }
  __syncthreads();
  {
    const int row = tid >> 5, lc = tid & 31;
    float s = 0.f, sq = 0.f;
#pragma unroll
    for (int e = 0; e < 24; ++e) {
      float x = fmaxf(As[row * HH + lc * 24 + e], 0.f);
      s += x; sq += x * x;
    }
#pragma unroll
    for (int d = 1; d < 32; d <<= 1) { s += __shfl_xor(s, d); sq += __shfl_xor(sq, d); }
    float mean = s * (1.0f / HH);
    float var = sq * (1.0f / HH) - mean * mean;
    float rstd = rsqrtf(var + 1e-12f);
#pragma unroll
    for (int e = 0; e < 24; ++e) {
      int cc = lc * 24 + e;
      float x = fmaxf(As[row * HH + cc], 0.f);
      As[row * HH + cc] = lw[cc] * (x - mean) * rstd + lb[cc];
    }
  }
  __syncthreads();
  const int c = tid & 31;
  const int col = (blockIdx.x << 5) + c;
  const int ks = tid >> 5;
  const float* Wp = job.W + (size_t)(ks * 96) * HH + col;
  float acc[8] = {};
#pragma unroll 8
  for (int k = 0; k < 96; ++k) {
    float wv = Wp[(size_t)k * HH];
    const float* ap = &As[ks * 96 + k];
#pragma unroll
    for (int m = 0; m < 8; ++m)
      acc[m] = fmaf(ap[m * HH], wv, acc[m]);
  }
#pragma unroll
  for (int m = 0; m < 8; ++m)
    part[ks * 256 + m * 32 + c] = acc[m];
  __syncthreads();
  const int m = tid >> 5;
  const int c2 = tid & 31;
  float s2 = 0.f;
#pragma unroll
  for (int k = 0; k < 8; ++k) s2 += part[k * 256 + m * 32 + c2];
  const int outcol = (blockIdx.x << 5) + c2;
  job.C[(size_t)m * HH + outcol] = s2 + job.bias[outcol];
}

// ============ fused head: relu+LN -> GEMM -> RoPE + tail, 16 rows/block x 256 blocks
__global__ __launch_bounds__(256) void head_fused(
    const ushort_t* __restrict__ Araw,
    const float* __restrict__ lnw, const float* __restrict__ lnb,
    const ushort_t* __restrict__ B,
    const float* __restrict__ head_b,
    const float* __restrict__ tail_w,
    const float* __restrict__ tail_b,
    float* __restrict__ qw, float* __restrict__ kw,
    float* __restrict__ bias2)
{
  __shared__ ushort_t As[16 * 64];
  __shared__ ushort_t Bs[128 * 64];
  __shared__ float tile[16][130];
  __shared__ float invt[32];
  __shared__ float2 rst[16];
  const int tid = threadIdx.x;
  const int bm = blockIdx.x * 16;
  const int l = tid & 63;
  const int w = tid >> 6;
  const int r8 = tid >> 3;
  const int sl = tid & 7;

  if (tid < 32) invt[tid] = powf(10000.0f, -(float)tid / 32.0f);

  {
    int row = tid >> 4, part = tid & 15;
    const ushort_t* rp = Araw + (size_t)(bm + row) * HH + part * 48;
    float s = 0.f, sq = 0.f;
#pragma unroll
    for (int c = 0; c < 6; ++c) {
      sx8 v = *(const sx8*)(rp + c * 8);
#pragma unroll
      for (int e = 0; e < 8; ++e) {
        float x = fmaxf(bf2f((ushort_t)v[e]), 0.f);
        s += x; sq += x * x;
      }
    }
#pragma unroll
    for (int d = 1; d < 16; d <<= 1) { s += __shfl_xor(s, d); sq += __shfl_xor(sq, d); }
    if (part == 0) {
      float mean = s * (1.0f / HH);
      float var = sq * (1.0f / HH) - mean * mean;
      rst[row] = make_float2(mean, rsqrtf(var + 1e-12f));
    }
  }
  __syncthreads();

  fx4 acc[2];
  acc[0] = (fx4)0.f; acc[1] = (fx4)0.f;

  for (int k0 = 0; k0 < HH; k0 += 64) {
#pragma unroll
    for (int i = 0; i < 4; ++i) {
      int row = i * 32 + r8;
      int srcs = sl ^ (row & 7);
      async_copy16((char*)Bs + i * 4096 + tid * 16,
                   B + (size_t)row * HH + k0 + srcs * 8);
    }
    if (tid < 128) {
      int row = tid >> 3;
      int slot = sl ^ (row & 7);
      int gk = k0 + slot * 8;
      sx8 v = *(const sx8*)(Araw + (size_t)(bm + row) * HH + gk);
      float4 w0 = *(const float4*)(lnw + gk);
      float4 w1 = *(const float4*)(lnw + gk + 4);
      float4 b0 = *(const float4*)(lnb + gk);
      float4 b1 = *(const float4*)(lnb + gk + 4);
      float wv[8] = {w0.x, w0.y, w0.z, w0.w, w1.x, w1.y, w1.z, w1.w};
      float bv[8] = {b0.x, b0.y, b0.z, b0.w, b1.x, b1.y, b1.z, b1.w};
      float2 mr = rst[row];
      sx8 ov;
#pragma unroll
      for (int e = 0; e < 8; ++e) {
        float x = fmaxf(bf2f((ushort_t)v[e]), 0.f);
        ov[e] = (short)f2bf(fmaf((x - mr.x) * mr.y, wv[e], bv[e]));
      }
      *(sx8*)((char*)As + row * 128 + sl * 16) = ov;
    }
    __syncthreads();
#pragma unroll
    for (int kk = 0; kk < 2; ++kk) {
      const int so = (l >> 4) + kk * 4;
      int ra = l & 15;
      sx8 av = *(const sx8*)((const char*)As + ra * 128 + ((so ^ (ra & 7)) * 16));
#pragma unroll
      for (int n = 0; n < 2; ++n) {
        int r = w * 32 + n * 16 + (l & 15);
        sx8 bv = *(const sx8*)((const char*)Bs + r * 128 + ((so ^ (r & 7)) * 16));
        acc[n] = __builtin_amdgcn_mfma_f32_16x16x32_bf16(av, bv, acc[n], 0, 0, 0);
      }
    }
    __syncthreads();
  }

  {
    const int rr0 = (l >> 4) * 4;
#pragma unroll
    for (int n = 0; n < 2; ++n) {
      int col = w * 32 + n * 16 + (l & 15);
      float bcol = head_b[col];
#pragma unroll
      for (int j = 0; j < 4; ++j)
        tile[rr0 + j][col] = acc[n][j] + bcol;
    }
  }
  __syncthreads();

#pragma unroll
  for (int it = 0; it < 2; ++it) {
    int t = tid + it * 256;
    int r = t >> 5, i = t & 31;
    int s = (bm + r) & 511;
    float ang = (float)s * invt[i];
    float sn = sinf(ang), cn = cosf(ang);
    float q0 = tile[r][4 * i + 0], k0 = tile[r][4 * i + 1];
    float q1 = tile[r][4 * i + 2], k1 = tile[r][4 * i + 3];
    float* qp = qw + (size_t)(bm + r) * 64 + i * 2;
    float* kp = kw + (size_t)(bm + r) * 64 + i * 2;
    qp[0] = q0 * cn - q1 * sn; qp[1] = q1 * cn + q0 * sn;
    kp[0] = k0 * cn - k1 * sn; kp[1] = k1 * cn + k0 * sn;
  }
  for (int t = tid; t < 16 * 24; t += 256) {
    int r = t / 24, c = t % 24;
    float acc2 = tail_b[c];
#pragma unroll 16
    for (int k = 0; k < 128; ++k) acc2 = fmaf(tile[r][k], tail_w[k * 24 + c], acc2);
    bias2[(size_t)(bm + r) * 24 + c] = acc2 * 0.5f;
  }
}

// ============ combined prep (+ zero center and relo)
struct TJob { const float* src; ushort_t* dst; int K, N, Kpad, rowOff; };
struct PrepArgs {
  TJob j[8];
  const float* bert; ushort_t* bert_bf;
  const float* rkb; const float* rvb; const float* sqb; const float* skb; const float* svb;
  float* b_merged;
  float* center;
  float* relo;
};
__global__ __launch_bounds__(256) void prep_all(PrepArgs pa)
{
  if (blockIdx.z < 8) {
    TJob jb = pa.j[blockIdx.z];
    int k0 = blockIdx.x * 32, n0 = blockIdx.y * 32;
    if (k0 >= jb.Kpad || n0 >= jb.N) return;
    __shared__ float t[32][33];
    int tx = threadIdx.x & 31, ty = threadIdx.x >> 5;
#pragma unroll
    for (int i = 0; i < 4; ++i) {
      int k = k0 + ty + i * 8;
      float v = 0.f;
      if (k < jb.K && n0 + tx < jb.N) v = jb.src[(size_t)k * jb.N + n0 + tx];
      t[ty + i * 8][tx] = v;
    }
    __syncthreads();
#pragma unroll
    for (int i = 0; i < 4; ++i) {
      int n = n0 + ty + i * 8;
      int k = k0 + tx;
      if (n < jb.N && k < jb.Kpad)
        jb.dst[(size_t)(jb.rowOff + n) * jb.Kpad + k] = f2bf(t[tx][ty + i * 8]);
    }
  } else {
    const int NB = BSROWS * 448;
    const int total = NB + 3840 + 2 * NBATCH * HH;
    int start = (blockIdx.y * 24 + blockIdx.x) * 256 + threadIdx.x;
    for (int i = start; i < total; i += 24 * 24 * 256) {
      if (i < NB) {
        int r = i / 448, c = i % 448;
        pa.bert_bf[i] = (c < 432) ? f2bf(pa.bert[(size_t)r * 432 + c]) : (ushort_t)0;
      } else if (i < NB + 3840) {
        int c = i - NB;
        float v;
        if (c < 768) v = pa.rkb[c];
        else if (c < 1536) v = pa.rvb[c - 768];
        else if (c < 2304) v = pa.sqb[c - 1536];
        else if (c < 3072) v = pa.skb[c - 2304];
        else v = pa.svb[c - 3072];
        pa.b_merged[c] = v;
      } else if (i < NB + 3840 + NBATCH * HH) {
        pa.center[i - NB - 3840] = 0.f;
      } else {
        pa.relo[i - NB - 3840 - NBATCH * HH] = 0.f;
      }
    }
  }
}

// ============ star attention, ushort2-vectorized, XCD-chunked blockIdx swizzle
__global__ __launch_bounds__(256) void sat_attn(
    const ushort_t* __restrict__ Qc, const ushort_t* __restrict__ Kc,
    const ushort_t* __restrict__ Vc, int ldq,
    const ushort_t* __restrict__ Kh0, const ushort_t* __restrict__ Vh0, int ldh,
    const float* __restrict__ Kcen, const float* __restrict__ Vcen,
    ushort_t* __restrict__ ctxb)
{
  int i = ((blockIdx.x & 7) << 9) | (blockIdx.x >> 3);  // XCD gets contiguous rows
  int b = i >> 9, s = i & 511;
  int lane = threadIdx.x & 63;
  int wave = threadIdx.x >> 6;
  size_t rb = (size_t)(b * SS + ((s + 1) & 511));
  size_t rs = (size_t)i;
  size_t ra = (size_t)(b * SS + (s == 0 ? (SS - 1) : 0));
  size_t rc = (size_t)b * HH;
  const int half = lane >> 5;
  const int d0 = (lane & 31) * 2;
#pragma unroll
  for (int it = 0; it < 2; ++it) {
    int p = wave + 4 * it;
    if (p >= 6) break;
    int off = (2 * p + half) * HDIM + d0;
    float2 q  = ldbf2(Qc + rs * ldq + off);
    float2 kb = ldbf2(Kc + rb * ldq + off);
    float2 ks = ldbf2(Kc + rs * ldq + off);
    float2 ka = ldbf2(Kc + ra * ldq + off);
    float2 kh = ldbf2(Kh0 + rs * ldh + off);
    float2 kc = *(const float2*)(Kcen + rc + off);
    float s0 = q.x * kb.x + q.y * kb.y;
    float s1 = q.x * ks.x + q.y * ks.y;
    float s2 = q.x * ka.x + q.y * ka.y;
    float s3 = q.x * kh.x + q.y * kh.y;
    float s4 = q.x * kc.x + q.y * kc.y;
#pragma unroll
    for (int d = 1; d < 32; d <<= 1) {
      s0 += __shfl_xor(s0, d); s1 += __shfl_xor(s1, d); s2 += __shfl_xor(s2, d);
      s3 += __shfl_xor(s3, d); s4 += __shfl_xor(s4, d);
    }
    const float sc = 0.125f;
    s0 *= sc; s1 *= sc; s2 *= sc; s3 *= sc; s4 *= sc;
    float mx = fmaxf(fmaxf(fmaxf(s0, s1), fmaxf(s2, s3)), s4);
    float e0 = __expf(s0 - mx), e1 = __expf(s1 - mx), e2 = __expf(s2 - mx);
    float e3 = __expf(s3 - mx), e4 = __expf(s4 - mx);
    float inv = 1.f / (e0 + e1 + e2 + e3 + e4);
    float2 vb = ldbf2(Vc + rb * ldq + off);
    float2 vs = ldbf2(Vc + rs * ldq + off);
    float2 va = ldbf2(Vc + ra * ldq + off);
    float2 vh = ldbf2(Vh0 + rs * ldh + off);
    float2 vc = *(const float2*)(Vcen + rc + off);
    float vx = e0 * vb.x + e1 * vs.x + e2 * va.x + e3 * vh.x + e4 * vc.x;
    float vy = e0 * vb.y + e1 * vs.y + e2 * va.y + e3 * vh.y + e4 * vc.y;
    uint32_t o = (uint32_t)f2bf(vx * inv) | ((uint32_t)f2bf(vy * inv) << 16);
    *(uint32_t*)(ctxb + rs * HH + off) = o;
  }
}

// ============ relu + layernorm over bf16 rows -> bf16 (iter-1 only)
__global__ __launch_bounds__(256) void relu_ln_bf(
    const ushort_t* __restrict__ x, const float* __restrict__ w, const float* __restrict__ b,
    ushort_t* __restrict__ ybf)
{
  int row = blockIdx.x;
  const ushort_t* xr = x + (size_t)row * HH;
  float v[3];
  float sum = 0.f, sumsq = 0.f;
#pragma unroll
  for (int j = 0; j < 3; ++j) {
    float t = bf2f(xr[threadIdx.x + j * 256]);
    t = fmaxf(t, 0.f);
    v[j] = t;
    sum += t; sumsq += t * t;
  }
#pragma unroll
  for (int d = 1; d < 64; d <<= 1) { sum += __shfl_xor(sum, d); sumsq += __shfl_xor(sumsq, d); }
  __shared__ float ws_[4], wsq_[4];
  int wave = threadIdx.x >> 6, lane = threadIdx.x & 63;
  if (lane == 0) { ws_[wave] = sum; wsq_[wave] = sumsq; }
  __syncthreads();
  sum = ws_[0] + ws_[1] + ws_[2] + ws_[3];
  sumsq = wsq_[0] + wsq_[1] + wsq_[2] + wsq_[3];
  float mean = sum * (1.0f / HH);
  float var = sumsq * (1.0f / HH) - mean * mean;
  float rstd = rsqrtf(var + 1e-12f);
#pragma unroll
  for (int j = 0; j < 3; ++j) {
    int cidx = threadIdx.x + j * 256;
    float o = w[cidx] * (v[j] - mean) * rstd + b[cidx];
    ybf[(size_t)row * HH + cidx] = f2bf(o);
  }
}

// ============ final logits
__global__ __launch_bounds__(256) void final_kernel(
    const float* __restrict__ qw, const float* __restrict__ kw,
    const float* __restrict__ bias2, const float* __restrict__ mask,
    float* __restrict__ out)
{
  int b = blockIdx.z;
  int mt = blockIdx.y * 32;
  int nt = blockIdx.x * 32;
  __shared__ float qs[32][68];
  __shared__ float ks[32][68];
  int t = threadIdx.x;
  {
    int idx = t * 8;
    int r = idx >> 6, c = idx & 63;
    const float* sq = qw + (size_t)(b * SS + mt + r) * 64 + c;
    const float* sk = kw + (size_t)(b * SS + nt + r) * 64 + c;
    *(float4*)&qs[r][c]     = *(const float4*)(sq);
    *(float4*)&qs[r][c + 4] = *(const float4*)(sq + 4);
    *(float4*)&ks[r][c]     = *(const float4*)(sk);
    *(float4*)&ks[r][c + 4] = *(const float4*)(sk + 4);
  }
  __syncthreads();
  int m = t >> 3;
  int n0 = (t & 7) * 4;
  float d0 = 0.f, d1 = 0.f, d2 = 0.f, d3 = 0.f;
#pragma unroll
  for (int d = 0; d < 64; d += 4) {
    float4 qv = *(const float4*)&qs[m][d];
    float4 k0 = *(const float4*)&ks[n0 + 0][d];
    float4 k1 = *(const float4*)&ks[n0 + 1][d];
    float4 k2 = *(const float4*)&ks[n0 + 2][d];
    float4 k3 = *(const float4*)&ks[n0 + 3][d];
    d0 += qv.x * k0.x + qv.y * k0.y + qv.z * k0.z + qv.w * k0.w;
    d1 += qv.x * k1.x + qv.y * k1.y + qv.z * k1.z + qv.w * k1.w;
    d2 += qv.x * k2.x + qv.y * k2.y + qv.z * k2.z + qv.w * k2.w;
    d3 += qv.x * k3.x + qv.y * k3.y + qv.z * k3.z + qv.w * k3.w;
  }
  int gm = mt + m;
  int gn = nt + n0;
  d0 *= 0.125f; d1 *= 0.125f; d2 *= 0.125f; d3 *= 0.125f;
  float mm = mask[b * SS + gm];
  float mn0 = mask[b * SS + gn + 0];
  float mn1 = mask[b * SS + gn + 1];
  float mn2 = mask[b * SS + gn + 2];
  float mn3 = mask[b * SS + gn + 3];
  const float* bmp  = bias2 + (size_t)(b * SS + gm) * 24;
  const float* bnp0 = bias2 + (size_t)(b * SS + gn + 0) * 24;
  const float* bnp1 = bias2 + (size_t)(b * SS + gn + 1) * 24;
  const float* bnp2 = bias2 + (size_t)(b * SS + gn + 2) * 24;
  const float* bnp3 = bias2 + (size_t)(b * SS + gn + 3) * 24;
#pragma unroll
  for (int h = 0; h < NLH; ++h) {
    float tb = bmp[2 * h + 1];
    float v0 = d0 + bnp0[2 * h] + tb;
    float v1 = d1 + bnp1[2 * h] + tb;
    float v2 = d2 + bnp2[2 * h] + tb;
    float v3 = d3 + bnp3[2 * h] + tb;
    v0 = v0 * mm + NEGV * (1.f - mm); v1 = v1 * mm + NEGV * (1.f - mm);
    v2 = v2 * mm + NEGV * (1.f - mm); v3 = v3 * mm + NEGV * (1.f - mm);
    v0 = v0 * mn0 + NEGV * (1.f - mn0); v1 = v1 * mn1 + NEGV * (1.f - mn1);
    v2 = v2 * mn2 + NEGV * (1.f - mn2); v3 = v3 * mn3 + NEGV * (1.f - mn3);
    if (gm > gn + 0) v0 -= 1000000000000.0f;
    if (gm > gn + 1) v1 -= 1000000000000.0f;
    if (gm > gn + 2) v2 -= 1000000000000.0f;
    if (gm > gn + 3) v3 -= 1000000000000.0f;
    float4 o = make_float4(v0, v1, v2, v3);
    *(float4*)(out + ((((size_t)(b * NLH + h)) * SS + gm) * SS + gn)) = o;
  }
}

extern "C" void kernel_launch(void* const* d_in, const int* in_sizes, int n_in,
                              void* d_out, int out_size, void* d_ws, size_t ws_size,
                              hipStream_t stream)
{
  const float* bert    = (const float*)d_in[0];
  const float* amask   = (const float*)d_in[1];
  const float* dense_w = (const float*)d_in[2];
  const float* dense_b = (const float*)d_in[3];
  const float* sat_qw  = (const float*)d_in[4];
  const float* sat_qb  = (const float*)d_in[5];
  const float* sat_kw  = (const float*)d_in[6];
  const float* sat_kb  = (const float*)d_in[7];
  const float* sat_vw  = (const float*)d_in[8];
  const float* sat_vb  = (const float*)d_in[9];
  const float* sat_ow  = (const float*)d_in[10];
  const float* sat_ob  = (const float*)d_in[11];
  const float* rel_qw  = (const float*)d_in[12];
  const float* rel_qb  = (const float*)d_in[13];
  const float* rel_kw  = (const float*)d_in[14];
  const float* rel_kb  = (const float*)d_in[15];
  const float* rel_vw  = (const float*)d_in[16];
  const float* rel_vb  = (const float*)d_in[17];
  const float* rel_ow  = (const float*)d_in[18];
  const float* rel_ob  = (const float*)d_in[19];
  const float* lns_w   = (const float*)d_in[20];
  const float* lns_b   = (const float*)d_in[21];
  const float* lnr_w   = (const float*)d_in[22];
  const float* lnr_b   = (const float*)d_in[23];
  const float* head_w  = (const float*)d_in[24];
  const float* head_b  = (const float*)d_in[25];
  const float* tail_w  = (const float*)d_in[26];
  const float* tail_b  = (const float*)d_in[27];

  float* out = (float*)d_out;
  char*  ws  = (char*)d_ws;

  size_t off = 0;
  auto alloc = [&](size_t bytes) { char* p = ws + off; off += (bytes + 255) & ~(size_t)255; return p; };
  ushort_t* bert_bf   = (ushort_t*)alloc((size_t)BSROWS * 448 * 2);
  ushort_t* Wt_dense  = (ushort_t*)alloc((size_t)768 * 448 * 2);
  ushort_t* Wt_big    = (ushort_t*)alloc((size_t)3840 * 768 * 2);
  ushort_t* Wt_satow  = (ushort_t*)alloc((size_t)768 * 768 * 2);
  ushort_t* Wt_head   = (ushort_t*)alloc((size_t)128 * 768 * 2);
  ushort_t* hidden0_bf= (ushort_t*)alloc((size_t)BSROWS * HH * 2);
  ushort_t* ctx_bf    = (ushort_t*)alloc((size_t)BSROWS * HH * 2);
  ushort_t* csA_bf    = (ushort_t*)alloc((size_t)BSROWS * HH * 2);
  float* b_merged = (float*)alloc(3840 * 4);
  float* center   = (float*)alloc(6144 * 4);
  float* Kcen     = (float*)alloc(6144 * 4);
  float* Vcen     = (float*)alloc(6144 * 4);
  float* Qr       = (float*)alloc(6144 * 4);
  float* Krc      = (float*)alloc(6144 * 4);
  float* Vrc      = (float*)alloc(6144 * 4);
  float* relo     = (float*)alloc(6144 * 4);
  float* bias2    = (float*)alloc((size_t)BSROWS * 24 * 4);
  float* qwbuf    = (float*)alloc((size_t)BSROWS * 64 * 4);
  float* kwbuf    = (float*)alloc((size_t)BSROWS * 64 * 4);

  ushort_t* QKV1_bf = (ushort_t*)out;
  ushort_t* tmp1_bf = QKV1_bf + (size_t)BSROWS * 2304;
  ushort_t* KrVr_bf = tmp1_bf + (size_t)BSROWS * 768;
  ushort_t* QKV2_bf = KrVr_bf + (size_t)BSROWS * 1536;
  ushort_t* tmp2_bf = tmp1_bf;

  dim3 blk(256);

  // 1. prep (+ zero center, relo)
  {
    PrepArgs pa;
    pa.j[0] = { dense_w, Wt_dense, 432, 768, 448, 0 };
    pa.j[1] = { rel_kw,  Wt_big,   768, 768, 768, 0 };
    pa.j[2] = { rel_vw,  Wt_big,   768, 768, 768, 768 };
    pa.j[3] = { sat_qw,  Wt_big,   768, 768, 768, 1536 };
    pa.j[4] = { sat_kw,  Wt_big,   768, 768, 768, 2304 };
    pa.j[5] = { sat_vw,  Wt_big,   768, 768, 768, 3072 };
    pa.j[6] = { sat_ow,  Wt_satow, 768, 768, 768, 0 };
    pa.j[7] = { head_w,  Wt_head,  768, 128, 768, 0 };
    pa.bert = bert; pa.bert_bf = bert_bf;
    pa.rkb = rel_kb; pa.rvb = rel_vb; pa.sqb = sat_qb; pa.skb = sat_kb; pa.svb = sat_vb;
    pa.b_merged = b_merged; pa.center = center; pa.relo = relo;
    prep_all<<<dim3(24, 24, 9), blk, 0, stream>>>(pa);
  }

  // 2. dense + fused column-mean
  gemm_bf16<<<dim3(192), blk, 0, stream>>>(bert_bf, 448, Wt_dense, 448, dense_b,
                                           nullptr, hidden0_bf, HH,
                                           nullptr, 0, 1 << 30, 448, 6, center);

  // 3. mega: iter-1 QKV GEMM + 5 center skinny projections
  {
    SmallJobs jobs;
    jobs.j[0] = { sat_kw, sat_kb, nullptr, Kcen };
    jobs.j[1] = { sat_vw, sat_vb, nullptr, Vcen };
    jobs.j[2] = { rel_qw, rel_qb, nullptr, Qr };
    jobs.j[3] = { rel_kw, rel_kb, nullptr, Krc };
    jobs.j[4] = { rel_vw, rel_vb, nullptr, Vrc };
    qkv_center<<<dim3(696), blk, 0, stream>>>(hidden0_bf, Wt_big + (size_t)1536 * 768,
                                              b_merged + 1536, QKV1_bf, jobs, center);
  }
  // 4. star attention 1
  sat_attn<<<BSROWS, 256, 0, stream>>>(QKV1_bf, QKV1_bf + 768, QKV1_bf + 1536, 2304,
                                       QKV1_bf + 768, QKV1_bf + 1536, 2304,
                                       Kcen, Vcen, ctx_bf);
  // 5. sat output proj + residual
  gemm_bf16<<<dim3(192), blk, 0, stream>>>(ctx_bf, HH, Wt_satow, HH, sat_ob,
                                           hidden0_bf, tmp1_bf, HH,
                                           nullptr, 0, 1 << 30, HH, 6, nullptr);
  // 6. relu+LN -> csA
  relu_ln_bf<<<BSROWS, 256, 0, stream>>>(tmp1_bf, lns_w, lns_b, csA_bf);

  // 7. relKV GEMM (480 blocks)
  gemm_bf16<<<dim3(480), blk, 0, stream>>>(csA_bf, HH, Wt_big, HH, b_merged,
                                           nullptr, KrVr_bf, 1536,
                                           nullptr, 0, 1 << 30, HH, 12, nullptr);
  // 8. mega: iter-2 QKV GEMM + rel attention (+proj atomics into relo)
  qkv2_rel<<<dim3(672), blk, 0, stream>>>(csA_bf, Wt_big + (size_t)1536 * 768,
                                          b_merged + 1536, QKV2_bf,
                                          Qr, Krc, KrVr_bf, Vrc, KrVr_bf + 768,
                                          rel_ow, relo);
  // 9. fused relu+LN(relo+ob+center) + iter-2 center projections
  {
    SmallJobs2 jobs;
    jobs.j[0] = { sat_kw, sat_kb, nullptr, Kcen };
    jobs.j[1] = { sat_vw, sat_vb, nullptr, Vcen };
    skinny_ln<<<dim3(24, 2), blk, 0, stream>>>(relo, rel_ob, center, lnr_w, lnr_b, jobs);
  }
  // 10. star attention 2
  sat_attn<<<BSROWS, 256, 0, stream>>>(QKV2_bf, QKV2_bf + 768, QKV2_bf + 1536, 2304,
                                       QKV1_bf + 768, QKV1_bf + 1536, 2304,
                                       Kcen, Vcen, ctx_bf);
  // 11. sat output proj 2 + residual (raw pre-LN out to tmp2)
  gemm_bf16<<<dim3(192), blk, 0, stream>>>(ctx_bf, HH, Wt_satow, HH, sat_ob,
                                           csA_bf, tmp2_bf, HH,
                                           nullptr, 0, 1 << 30, HH, 6, nullptr);
  // 12. fused relu+LN + head GEMM + rope + tail
  head_fused<<<256, blk, 0, stream>>>(tmp2_bf, lns_w, lns_b, Wt_head, head_b,
                                      tail_w, tail_b, qwbuf, kwbuf, bias2);
  // 13. final logits
  final_kernel<<<dim3(16, 16, 8), 256, 0, stream>>>(qwbuf, kwbuf, bias2, amask, out);
}